// Round 7
// baseline (1795.314 us; speedup 1.0000x reference)
//
#include <hip/hip_runtime.h>

// ---------------------------------------------------------------------------
// Bayesian LSTM forward: B=256, L=512, K=128, H=512 (4H = 2048)
//
// 256 persistent blocks (1/CU, cooperative). Block = (pair p 0..7, slice s
// 0..31 of 16 hidden units), handling TWO groups: gA=2p, gB=2p+1 (16 batch
// rows each). The two recurrences share weight registers and interleave in
// one instruction stream so each group's L3 gather latency hides under the
// other group's GEMM+epilogue (round-6 showed one recurrence/CU leaves the
// full L3 RTT exposed every step).
//
// Publish: h as 2 packed bf16 per word; 2-bit step tag lives in bits 14/30
// (always 0 for |h|<2). Consumer: d = w ^ pat; valid iff (OR of all d) has
// bits 14/30 clear; d IS the cleaned operand. Ring-2 buffers, tag=(T&3),
// zero-init => poison/stale always mismatches; flow control by the per-group
// all-to-all dependence. Fire-and-forget sc1 stores; no flags, no fences.
//
// K-split: wave w owns k-tiles {w,w+4,w+8,w+12} (h) + {16+w} (x), all 4 gate
// col-tiles => A-tile read once per block (4x less LDS traffic); partial
// gates combined via 4 LDS buffers, summed deterministically in gate math.
// ---------------------------------------------------------------------------

typedef __attribute__((ext_vector_type(8))) __bf16 bf16x8;
typedef __attribute__((ext_vector_type(4))) float f32x4;
typedef __attribute__((ext_vector_type(8))) unsigned short us8;
typedef __attribute__((ext_vector_type(4))) unsigned int u32x4;

union U8 { us8 v; unsigned short u[8]; };

#define WFRAG_OFF   0u           // 1310720 ushort = 2621440 B
#define HBUF_OFF    2621440u     // 2 bufs * 65536 u32 = 524288 B
#define PART_OFF    3178496u     // 512 float
#define WS_NEEDED   3180544u

#define LOSS_OFF    67108864u
#define HT_OFF      67108865u
#define CT_OFF      67239937u

#define TAGMASK 0x40004000u

__device__ __forceinline__ unsigned short f2bf(float f) {
  unsigned int u = __builtin_bit_cast(unsigned int, f);
  unsigned int r = (u + 0x7FFFu + ((u >> 16) & 1u)) >> 16;
  return (unsigned short)r;
}
__device__ __forceinline__ unsigned int pk_bf16(float a, float b) {
  unsigned int r;
  asm("v_cvt_pk_bf16_f32 %0, %1, %2" : "=v"(r) : "v"(a), "v"(b));
  return r;
}
__device__ __forceinline__ float sigm(float v) {
  return __builtin_amdgcn_rcpf(1.0f + __expf(-v));
}
__device__ __forceinline__ float tanh_f(float v) {
  return 1.0f - 2.0f * __builtin_amdgcn_rcpf(__expf(2.0f * v) + 1.0f);
}

#define BAR_LGKM() asm volatile("s_waitcnt lgkmcnt(0)\n\ts_barrier" ::: "memory")

#define MFMA(a, b, c) __builtin_amdgcn_mfma_f32_16x16x32_bf16( \
    __builtin_bit_cast(bf16x8, a), __builtin_bit_cast(bf16x8, b), c, 0, 0, 0)

// issue 64B gather (4 x dwordx4, agent scope), NO wait
#define LDH_ISSUE(d0,d1,d2,d3,p)                                         \
  asm volatile("global_load_dwordx4 %0, %4, off sc1\n\t"                 \
               "global_load_dwordx4 %1, %4, off offset:16 sc1\n\t"       \
               "global_load_dwordx4 %2, %4, off offset:32 sc1\n\t"       \
               "global_load_dwordx4 %3, %4, off offset:48 sc1"           \
               : "=&v"(d0), "=&v"(d1), "=&v"(d2), "=&v"(d3)              \
               : "v"(p) : "memory")
// drain + tie the gathered regs so later uses can't be hoisted above
#define VM0_4(d0,d1,d2,d3)                                               \
  asm volatile("s_waitcnt vmcnt(0)"                                      \
               : "+v"(d0), "+v"(d1), "+v"(d2), "+v"(d3) :: "memory")

// ---------------- prep: weight fragments (bf16, MFMA B layout) + ring zero --
// frag id: ((s*4 + w)*20 + fr)*64 + lane, fr = gate*5 + j, kt = w + 4*j
__global__ void prep_w(const float* __restrict__ whh, const float* __restrict__ wih,
                       unsigned short* __restrict__ w_frag,
                       unsigned int* __restrict__ h_words) {
  int gid = blockIdx.x * 256 + threadIdx.x;
  if (gid < 131072) h_words[gid] = 0;          // tag 00: poison can't validate
  if (gid >= 163840) return;
  int lane = gid & 63;
  int t3 = gid >> 6;                 // 0..2559
  int fr = t3 % 20;
  int w  = (t3 / 20) & 3;
  int s  = t3 / 80;                  // 0..31
  int g  = fr / 5, j = fr % 5;
  int kt = w + 4 * j;
  int gc = (g << 9) + (s << 4) + (lane & 15);
  int kbase = (kt << 5) + ((lane >> 4) << 3);
  U8 p;
#pragma unroll
  for (int jj = 0; jj < 8; ++jj) {
    int k = kbase + jj;
    float v = (k < 512) ? whh[k * 2048 + gc] : wih[(k - 512) * 2048 + gc];
    p.u[jj] = f2bf(v);
  }
  *(us8*)&w_frag[(size_t)gid * 8] = p.v;
}

// ---------------- bayes loss: block partials ---------------------------------
__global__ void loss_k(const float* __restrict__ whh, const float* __restrict__ wih,
                       const float* __restrict__ bias,
                       const float* __restrict__ whh_mu, const float* __restrict__ whh_rho,
                       const float* __restrict__ wih_mu, const float* __restrict__ wih_rho,
                       const float* __restrict__ b_mu, const float* __restrict__ b_rho,
                       float* __restrict__ partials) {
  int gid = blockIdx.x * 256 + threadIdx.x;
  float acc = 0.f;
  for (int idx = gid; idx < 1312768; idx += 131072) {
    float p, mu, rho;
    if (idx < 1048576)      { p = whh[idx];           mu = whh_mu[idx];           rho = whh_rho[idx]; }
    else if (idx < 1310720) { int i = idx - 1048576;  p = wih[i]; mu = wih_mu[i]; rho = wih_rho[i]; }
    else                    { int i = idx - 1310720;  p = bias[i]; mu = b_mu[i];  rho = b_rho[i]; }
    float sig = log1pf(__expf(rho));
    float d = p - mu;
    float vari = -0.57236494f - logf(sig) - d * d / (2.f * sig * sig);
    float lp1 = -0.91893853f - 0.5f * p * p;
    float lp2 = 5.98881675f - 500000.f * p * p;
    float prior = logf(0.5f * (__expf(lp1) + __expf(lp2)));
    acc += vari - prior;
  }
#pragma unroll
  for (int off = 32; off; off >>= 1) acc += __shfl_down(acc, off, 64);
  __shared__ float wsum[4];
  if ((threadIdx.x & 63) == 0) wsum[threadIdx.x >> 6] = acc;
  __syncthreads();
  if (threadIdx.x == 0) partials[blockIdx.x] = wsum[0] + wsum[1] + wsum[2] + wsum[3];
}

// ---------------- persistent LSTM kernel -------------------------------------
__launch_bounds__(256, 1)
__global__ void lstm_k(const float* __restrict__ x,
                       const unsigned short* __restrict__ w_frag,
                       const float* __restrict__ bias,
                       unsigned int* __restrict__ h_words,
                       const float* __restrict__ partials,
                       float* __restrict__ out) {
  __shared__ unsigned short A_sh[2][16][648];  // per group: h(0..511)|x(512..639)
  __shared__ float PB[4][16][68];              // per-wave partial gates

  const int tid  = threadIdx.x;
  const int lane = tid & 63;
  const int wv   = tid >> 6;
  const int bid  = blockIdx.x;
  const int p = bid & 7;
  const int s = bid >> 3;                      // slice 0..31 (16 units)
  const int gA = p << 1, gB = (p << 1) | 1;
  const int b0A = gA << 4, b0B = gB << 4;

  // ---- stationary B fragments: 20 x bf16x8 (shared by both groups) --------
  us8 bfr[20];
  {
    const us8* wfp = (const us8*)w_frag + (size_t)((s * 4 + wv) * 20) * 64;
#pragma unroll
    for (int fr = 0; fr < 20; ++fr) bfr[fr] = wfp[fr * 64 + lane];
  }

  // ---- epilogue mapping: thread -> (row r, unit u) ------------------------
  const int r = tid >> 4;
  const int u = tid & 15;
  const int ug = (s << 4) + u;
  const float bi = bias[ug], bf_ = bias[512 + ug];
  const float bg = bias[1024 + ug], bo = bias[1536 + ug];
  float cA = 0.f, cB = 0.f;

  const unsigned short* arowA = &A_sh[0][lane & 15][(lane >> 4) << 3];
  const unsigned short* arowB = &A_sh[1][lane & 15][(lane >> 4) << 3];

  const unsigned gb_off  = (r << 8) + (u << 4);            // gather word base
  const unsigned pub_off = (r << 8) + (s << 3) + (u >> 1); // publish word

  // ---- x prefetch (1 step ahead, register-resident) -----------------------
  const int f8 = u << 3;
  const float* xbA = x + (((size_t)(b0A + r)) << 16) + f8;
  const float* xbB = x + (((size_t)(b0B + r)) << 16) + f8;
  float4 xA0 = *(const float4*)xbA, xA1 = *(const float4*)(xbA + 4);
  float4 xB0 = *(const float4*)xbB, xB1 = *(const float4*)(xbB + 4);

  for (int t = 0; t < 512; ++t) {
    const unsigned patC = (((unsigned)t & 1u) << 14) | ((((unsigned)t >> 1) & 1u) << 30);
    const unsigned* wpA = h_words + (((unsigned)t & 1u) << 16) + (gA << 12) + gb_off;
    const unsigned* wpB = h_words + (((unsigned)t & 1u) << 16) + (gB << 12) + gb_off;

    // ---- stage x_t for BOTH groups (from prefetch regs) -------------------
    {
      u32x4 xv;
      xv[0] = pk_bf16(xA0.x, xA0.y); xv[1] = pk_bf16(xA0.z, xA0.w);
      xv[2] = pk_bf16(xA1.x, xA1.y); xv[3] = pk_bf16(xA1.z, xA1.w);
      *(u32x4*)&A_sh[0][r][512 + f8] = xv;
      xv[0] = pk_bf16(xB0.x, xB0.y); xv[1] = pk_bf16(xB0.z, xB0.w);
      xv[2] = pk_bf16(xB1.x, xB1.y); xv[3] = pk_bf16(xB1.z, xB1.w);
      *(u32x4*)&A_sh[1][r][512 + f8] = xv;
    }
    // ---- issue gather A (checked after x-MFMA A) --------------------------
    u32x4 vA0, vA1, vA2, vA3;
    if (t > 0) LDH_ISSUE(vA0, vA1, vA2, vA3, wpA);
    BAR_LGKM();                                          // B1: x staged

    // ================= group A half =================
    f32x4 acc0 = {0.f,0.f,0.f,0.f}, acc1 = {0.f,0.f,0.f,0.f};
    f32x4 acc2 = {0.f,0.f,0.f,0.f}, acc3 = {0.f,0.f,0.f,0.f};
    {
      us8 ax = *(const us8*)(arowA + ((16 + wv) << 5));
      acc0 = MFMA(ax, bfr[4], acc0);
      acc1 = MFMA(ax, bfr[9], acc1);
      acc2 = MFMA(ax, bfr[14], acc2);
      acc3 = MFMA(ax, bfr[19], acc3);
    }
    if (t > 0) {
      VM0_4(vA0, vA1, vA2, vA3);
      const u32x4 ps = {patC, patC, patC, patC};
      while (true) {
        u32x4 d0 = vA0 ^ ps, d1 = vA1 ^ ps, d2 = vA2 ^ ps, d3 = vA3 ^ ps;
        u32x4 o4 = (d0 | d1) | (d2 | d3);
        unsigned orr = (o4[0] | o4[1]) | (o4[2] | o4[3]);
        if (__all((orr & TAGMASK) == 0)) {
          unsigned short* dst = &A_sh[0][r][u << 5];
          *(u32x4*)dst = d0; *(u32x4*)(dst + 8) = d1;
          *(u32x4*)(dst + 16) = d2; *(u32x4*)(dst + 24) = d3;
          break;
        }
        LDH_ISSUE(vA0, vA1, vA2, vA3, wpA);
        VM0_4(vA0, vA1, vA2, vA3);
      }
    }
    BAR_LGKM();                                          // B2: h_A staged

    // ---- issue gather B early (hides under GEMM A + epilogue A) -----------
    u32x4 vB0, vB1, vB2, vB3;
    if (t > 0) LDH_ISSUE(vB0, vB1, vB2, vB3, wpB);
    // ---- issue x prefetch for t+1 (waited at B's check, consumed next t) --
    if (t < 511) {
      const float* xa = xbA + ((size_t)(t + 1) << 7);
      xA0 = *(const float4*)xa; xA1 = *(const float4*)(xa + 4);
      const float* xb = xbB + ((size_t)(t + 1) << 7);
      xB0 = *(const float4*)xb; xB1 = *(const float4*)(xb + 4);
    }

    if (t > 0) {
#pragma unroll
      for (int j = 0; j < 4; ++j) {
        us8 ah = *(const us8*)(arowA + ((wv + (j << 2)) << 5));
        acc0 = MFMA(ah, bfr[j], acc0);
        acc1 = MFMA(ah, bfr[5 + j], acc1);
        acc2 = MFMA(ah, bfr[10 + j], acc2);
        acc3 = MFMA(ah, bfr[15 + j], acc3);
      }
    }
    {
      const int crow = (lane >> 4) << 2;
      const int cc = lane & 15;
#pragma unroll
      for (int q = 0; q < 4; ++q) {
        PB[wv][crow + q][cc]      = acc0[q];
        PB[wv][crow + q][16 + cc] = acc1[q];
        PB[wv][crow + q][32 + cc] = acc2[q];
        PB[wv][crow + q][48 + cc] = acc3[q];
      }
    }
    BAR_LGKM();                                          // B3: gates A ready

    float hA;
    {
      float gi = ((PB[0][r][u]      + PB[1][r][u])      + (PB[2][r][u]      + PB[3][r][u]))      + bi;
      float gf = ((PB[0][r][16 + u] + PB[1][r][16 + u]) + (PB[2][r][16 + u] + PB[3][r][16 + u])) + bf_;
      float gg = ((PB[0][r][32 + u] + PB[1][r][32 + u]) + (PB[2][r][32 + u] + PB[3][r][32 + u])) + bg;
      float go = ((PB[0][r][48 + u] + PB[1][r][48 + u]) + (PB[2][r][48 + u] + PB[3][r][48 + u])) + bo;
      float it_ = sigm(gi), ft_ = sigm(gf), ot_ = sigm(go);
      cA = ft_ * cA + it_ * tanh_f(gg);
      hA = ot_ * tanh_f(cA);
    }
    {
      const unsigned T = (unsigned)(t + 1);
      const unsigned patP = ((T & 1u) << 14) | (((T >> 1) & 1u) << 30);
      float hn = __shfl_xor(hA, 1);
      if (!(u & 1)) {
        unsigned w = pk_bf16(hA, hn) | patP;
        unsigned* pp = h_words + ((T & 1u) << 16) + (gA << 12) + pub_off;
        __hip_atomic_store(pp, w, __ATOMIC_RELAXED, __HIP_MEMORY_SCOPE_AGENT);
      }
      out[((((size_t)(b0A + r)) << 9) + (size_t)t << 9) + ug] = hA;
      if (t == 511) {
        out[HT_OFF + (((size_t)(b0A + r)) << 9) + ug] = hA;
        out[CT_OFF + (((size_t)(b0A + r)) << 9) + ug] = cA;
      }
    }

    // ================= group B half =================
    acc0 = (f32x4){0.f,0.f,0.f,0.f}; acc1 = (f32x4){0.f,0.f,0.f,0.f};
    acc2 = (f32x4){0.f,0.f,0.f,0.f}; acc3 = (f32x4){0.f,0.f,0.f,0.f};
    {
      us8 ax = *(const us8*)(arowB + ((16 + wv) << 5));
      acc0 = MFMA(ax, bfr[4], acc0);
      acc1 = MFMA(ax, bfr[9], acc1);
      acc2 = MFMA(ax, bfr[14], acc2);
      acc3 = MFMA(ax, bfr[19], acc3);
    }
    if (t > 0) {
      VM0_4(vB0, vB1, vB2, vB3);
      const u32x4 ps = {patC, patC, patC, patC};
      while (true) {
        u32x4 d0 = vB0 ^ ps, d1 = vB1 ^ ps, d2 = vB2 ^ ps, d3 = vB3 ^ ps;
        u32x4 o4 = (d0 | d1) | (d2 | d3);
        unsigned orr = (o4[0] | o4[1]) | (o4[2] | o4[3]);
        if (__all((orr & TAGMASK) == 0)) {
          unsigned short* dst = &A_sh[1][r][u << 5];
          *(u32x4*)dst = d0; *(u32x4*)(dst + 8) = d1;
          *(u32x4*)(dst + 16) = d2; *(u32x4*)(dst + 24) = d3;
          break;
        }
        LDH_ISSUE(vB0, vB1, vB2, vB3, wpB);
        VM0_4(vB0, vB1, vB2, vB3);
      }
    }
    BAR_LGKM();                                          // B4: h_B staged

    if (t > 0) {
#pragma unroll
      for (int j = 0; j < 4; ++j) {
        us8 ah = *(const us8*)(arowB + ((wv + (j << 2)) << 5));
        acc0 = MFMA(ah, bfr[j], acc0);
        acc1 = MFMA(ah, bfr[5 + j], acc1);
        acc2 = MFMA(ah, bfr[10 + j], acc2);
        acc3 = MFMA(ah, bfr[15 + j], acc3);
      }
    }
    {
      const int crow = (lane >> 4) << 2;
      const int cc = lane & 15;
#pragma unroll
      for (int q = 0; q < 4; ++q) {
        PB[wv][crow + q][cc]      = acc0[q];
        PB[wv][crow + q][16 + cc] = acc1[q];
        PB[wv][crow + q][32 + cc] = acc2[q];
        PB[wv][crow + q][48 + cc] = acc3[q];
      }
    }
    BAR_LGKM();                                          // B5: gates B ready

    float hB;
    {
      float gi = ((PB[0][r][u]      + PB[1][r][u])      + (PB[2][r][u]      + PB[3][r][u]))      + bi;
      float gf = ((PB[0][r][16 + u] + PB[1][r][16 + u]) + (PB[2][r][16 + u] + PB[3][r][16 + u])) + bf_;
      float gg = ((PB[0][r][32 + u] + PB[1][r][32 + u]) + (PB[2][r][32 + u] + PB[3][r][32 + u])) + bg;
      float go = ((PB[0][r][48 + u] + PB[1][r][48 + u]) + (PB[2][r][48 + u] + PB[3][r][48 + u])) + bo;
      float it_ = sigm(gi), ft_ = sigm(gf), ot_ = sigm(go);
      cB = ft_ * cB + it_ * tanh_f(gg);
      hB = ot_ * tanh_f(cB);
    }
    {
      const unsigned T = (unsigned)(t + 1);
      const unsigned patP = ((T & 1u) << 14) | (((T >> 1) & 1u) << 30);
      float hn = __shfl_xor(hB, 1);
      if (!(u & 1)) {
        unsigned w = pk_bf16(hB, hn) | patP;
        unsigned* pp = h_words + ((T & 1u) << 16) + (gB << 12) + pub_off;
        __hip_atomic_store(pp, w, __ATOMIC_RELAXED, __HIP_MEMORY_SCOPE_AGENT);
      }
      out[((((size_t)(b0B + r)) << 9) + (size_t)t << 9) + ug] = hB;
      if (t == 511) {
        out[HT_OFF + (((size_t)(b0B + r)) << 9) + ug] = hB;
        out[CT_OFF + (((size_t)(b0B + r)) << 9) + ug] = cB;
      }
    }
    BAR_LGKM();   // B6: PB safe to overwrite next iter; A_sh x-stage safe
  }

  // ---- block 0: finalize deterministic loss sum ---------------------------
  if (bid == 0) {
    float v = partials[tid] + partials[tid + 256];
#pragma unroll
    for (int off = 32; off; off >>= 1) v += __shfl_down(v, off, 64);
    __shared__ float lw[4];
    if ((tid & 63) == 0) lw[tid >> 6] = v;
    __syncthreads();
    if (tid == 0) out[LOSS_OFF] = lw[0] + lw[1] + lw[2] + lw[3];
  }
}

// ---------------------------------------------------------------------------
extern "C" void kernel_launch(void* const* d_in, const int* in_sizes, int n_in,
                              void* d_out, int out_size, void* d_ws, size_t ws_size,
                              hipStream_t stream) {
  if (ws_size < WS_NEEDED) return;
  const float* x       = (const float*)d_in[0];
  const float* whh     = (const float*)d_in[1];
  const float* wih     = (const float*)d_in[2];
  const float* bias    = (const float*)d_in[3];
  const float* whh_mu  = (const float*)d_in[4];
  const float* whh_rho = (const float*)d_in[5];
  const float* wih_mu  = (const float*)d_in[6];
  const float* wih_rho = (const float*)d_in[7];
  const float* b_mu    = (const float*)d_in[8];
  const float* b_rho   = (const float*)d_in[9];
  char* ws = (char*)d_ws;
  unsigned short* w_frag  = (unsigned short*)(ws + WFRAG_OFF);
  unsigned int*   h_words = (unsigned int*)(ws + HBUF_OFF);
  float*          parts   = (float*)(ws + PART_OFF);
  float*          out     = (float*)d_out;

  prep_w<<<640, 256, 0, stream>>>(whh, wih, w_frag, h_words);
  loss_k<<<512, 256, 0, stream>>>(whh, wih, bias, whh_mu, whh_rho,
                                  wih_mu, wih_rho, b_mu, b_rho, parts);

  void* kargs[6];
  kargs[0] = (void*)&x;
  kargs[1] = (void*)&w_frag;
  kargs[2] = (void*)&bias;
  kargs[3] = (void*)&h_words;
  kargs[4] = (void*)&parts;
  kargs[5] = (void*)&out;
  hipLaunchCooperativeKernel((const void*)lstm_k, dim3(256), dim3(256),
                             kargs, 0, stream);
}